// Round 10
// baseline (125.267 us; speedup 1.0000x reference)
//
#include <hip/hip_runtime.h>
#include <hip/hip_bf16.h>
#include <stdint.h>
#include <stddef.h>

// ---------------------------------------------------------------------------
// TimeSeriesAttention: out = softmax((x Wq + bq)(x Wk + bk)^T / 16) (x Wv + bv)
// B=4, S=4096, H=256, fp32 in/out.
// v10: V direct global->VGPR (L1-served; all 4 waves share the tile), LDS
//      holds only the K double-buffer (2x16KB). Halves the LDS-port traffic
//      that bound r4-r9. V time-shared in an 8-frag register window to hold
//      total regs < 256 (2 waves/SIMD). One vmcnt(0)+barrier per tile.
//      32x32 MFMA fragment math identical to v9 (verified).
// ---------------------------------------------------------------------------

typedef __bf16 bf16;
typedef _Float16 f16;
typedef __attribute__((ext_vector_type(4))) __bf16 bf16x4;
typedef __attribute__((ext_vector_type(8))) __bf16 bf16x8;
typedef __attribute__((ext_vector_type(4))) float f32x4;
typedef __attribute__((ext_vector_type(16))) float f32x16;
typedef __attribute__((ext_vector_type(4))) _Float16 f16x4;
typedef __attribute__((ext_vector_type(8))) _Float16 f16x8;

#define S_LEN 4096
#define HDIM  256
#define PSTRIDE ((size_t)16384 * 256)   // elems per fp16 partial buffer (8MB)

__device__ __forceinline__ f32x4 mfma16(bf16x8 a, bf16x8 b, f32x4 c) {
  return __builtin_amdgcn_mfma_f32_16x16x32_bf16(a, b, c, 0, 0, 0);
}
__device__ __forceinline__ f32x16 mfma32(bf16x8 a, bf16x8 b, f32x16 c) {
  return __builtin_amdgcn_mfma_f32_32x32x16_bf16(a, b, c, 0, 0, 0);
}

__device__ __forceinline__ void gld_lds16(const void* g, void* l) {
  __builtin_amdgcn_global_load_lds(
      (const __attribute__((address_space(1))) void*)g,
      (__attribute__((address_space(3))) void*)l, 16, 0, 0);
}

__device__ __forceinline__ float fast_exp2(float x) {
  float r;
  asm("v_exp_f32 %0, %1" : "=v"(r) : "v"(x));
  return r;
}

#define BAR_VMCNT0() do { \
  asm volatile("s_waitcnt vmcnt(0)" ::: "memory"); \
  __builtin_amdgcn_s_barrier(); \
  asm volatile("" ::: "memory"); \
  __builtin_amdgcn_sched_barrier(0); } while (0)

// ---------------------------------------------------------------------------
// Kernel 1: WT_m[d][h] = (bf16) W_m[h][d].  192 blocks = 3 m x 64 (32x32) tiles.
// ---------------------------------------------------------------------------
__global__ __launch_bounds__(256) void wt_kernel(
    const float* __restrict__ Wq, const float* __restrict__ Wk,
    const float* __restrict__ Wv, bf16* __restrict__ WT) {
  __shared__ float tile[32][33];
  int bid = blockIdx.x;
  int m = bid >> 6;
  int t = bid & 63;
  int hb = (t >> 3) * 32;
  int db = (t & 7) * 32;
  const float* W = (m == 0) ? Wq : (m == 1) ? Wk : Wv;
  bf16* o = WT + m * 65536;
  int ty = threadIdx.x >> 3;
  int tx = threadIdx.x & 7;
  float4 v = *(const float4*)(W + (size_t)(hb + ty) * 256 + db + tx * 4);
  tile[ty][tx * 4 + 0] = v.x; tile[ty][tx * 4 + 1] = v.y;
  tile[ty][tx * 4 + 2] = v.z; tile[ty][tx * 4 + 3] = v.w;
  __syncthreads();
  bf16x4 h = {(bf16)tile[tx * 4 + 0][ty], (bf16)tile[tx * 4 + 1][ty],
              (bf16)tile[tx * 4 + 2][ty], (bf16)tile[tx * 4 + 3][ty]};
  *(bf16x4*)(o + (size_t)(db + ty) * 256 + hb + tx * 4) = h;
}

// ---------------------------------------------------------------------------
// Kernel 2: fused QKV projection (v9 structure, unchanged; emits 32x32
//   fragment order: K frag c slot (l,e) = K[t*32+(l&31)][16c+8(l>>5)+e];
//   V frag c2=dt*2+ks slot (l,e) = V[t*32+(e&3)+8((e>>2)+2ks)+4(l>>5)][dt*32+(l&31)])
// ---------------------------------------------------------------------------
__global__ __launch_bounds__(256, 3) void proj_kernel(
    const float* __restrict__ x, const bf16* __restrict__ WT,
    const float* __restrict__ bq, const float* __restrict__ bk,
    const float* __restrict__ bv,
    bf16* __restrict__ Qb, char* __restrict__ KV) {
  __shared__ __align__(16) char smem[34816];
  int tid = threadIdx.x;
  int row0 = blockIdx.x * 64;
  int m = blockIdx.y;

#pragma unroll
  for (int i = 0; i < 16; ++i) {
    int c = i * 256 + tid;
    int r = c >> 6, c4 = c & 63;
    float4 v = *(const float4*)(x + (size_t)(row0 + r) * 256 + c4 * 4);
    bf16x4 b4 = {(bf16)v.x, (bf16)v.y, (bf16)v.z, (bf16)v.w};
    *(bf16x4*)(smem + r * 512 + ((c4 * 8) ^ ((r & 7) << 4))) = b4;
  }
  __syncthreads();

  int w = tid >> 6, lane = tid & 63, lg = lane >> 4, l15 = lane & 15;
  int ar = w * 16 + l15;
  int swz = (l15 & 7) << 4;
  bf16x8 af[8];
#pragma unroll
  for (int ks = 0; ks < 8; ++ks)
    af[ks] = *(const bf16x8*)(smem + ar * 512 + ((ks * 64 + lg * 16) ^ swz));
  __syncthreads();

  int b = row0 >> 12, t0 = (row0 & 4095) >> 5;
  const bf16* Wm = WT + m * 65536;
  const float* bias = (m == 0) ? bq : (m == 1) ? bk : bv;

#pragma unroll
  for (int i = 0; i < 4; ++i) {
    int c = w * 4 + i;
    gld_lds16(Wm + (c * 16 + l15) * 256 + lg * 8, smem + c * 1024 + lane * 16);
  }
  __syncthreads();

  f32x4 acc[16];
#pragma unroll
  for (int dt = 0; dt < 16; ++dt) acc[dt] = f32x4{0.f, 0.f, 0.f, 0.f};

  for (int ks = 0; ks < 8; ++ks) {
    const char* wb = smem + (ks & 1) * 16384;
    if (ks + 1 < 8) {
      char* wn = smem + ((ks + 1) & 1) * 16384;
#pragma unroll
      for (int i = 0; i < 4; ++i) {
        int c = w * 4 + i;
        gld_lds16(Wm + (c * 16 + l15) * 256 + (ks + 1) * 32 + lg * 8,
                  wn + c * 1024 + lane * 16);
      }
    }
    __builtin_amdgcn_s_setprio(1);
#pragma unroll
    for (int dt = 0; dt < 16; ++dt) {
      bf16x8 wf = *(const bf16x8*)(wb + dt * 1024 + lane * 16);
      acc[dt] = mfma16(af[ks], wf, acc[dt]);
    }
    __builtin_amdgcn_s_setprio(0);
    __syncthreads();
  }

  if (m == 0) {
#pragma unroll
    for (int dt = 0; dt < 16; ++dt) {
      float bb = bias[dt * 16 + l15];
#pragma unroll
      for (int rr = 0; rr < 4; ++rr) {
        int srow = row0 + w * 16 + 4 * lg + rr;
        Qb[(size_t)srow * 256 + dt * 16 + l15] = (bf16)(acc[dt][rr] + bb);
      }
    }
  } else if (m == 1) {
    // K: tile [s_local][d] in LDS (stride 264), emit 32x32 A-frag order
    bf16* sm16 = (bf16*)smem;
#pragma unroll
    for (int dt = 0; dt < 16; ++dt) {
      float bb = bias[dt * 16 + l15];
#pragma unroll
      for (int rr = 0; rr < 4; ++rr) {
        int sl = w * 16 + 4 * lg + rr;
        sm16[sl * 264 + dt * 16 + l15] = (bf16)(acc[dt][rr] + bb);
      }
    }
    __syncthreads();
    int tt = tid >> 7, c = (tid >> 3) & 15, j0 = (tid & 7) * 8;
    char* dst = KV + ((size_t)(b * 128 + t0 + tt)) * 32768 + c * 1024 + j0 * 16;
#pragma unroll
    for (int u = 0; u < 8; ++u) {
      int l = j0 + u;
      bf16x8 v8 = *(const bf16x8*)(sm16 + (tt * 32 + (l & 31)) * 264
                                   + c * 16 + (l >> 5) * 8);
      *(bf16x8*)(dst + u * 16) = v8;
    }
  } else {
    // V: transposed tile smV[d][sl] (stride 68), emit pi-permuted frag order
    bf16* smV = (bf16*)smem;
#pragma unroll
    for (int dt = 0; dt < 16; ++dt) {
      float bb = bias[dt * 16 + l15];
      bf16x4 h = {(bf16)(acc[dt][0] + bb), (bf16)(acc[dt][1] + bb),
                  (bf16)(acc[dt][2] + bb), (bf16)(acc[dt][3] + bb)};
      *(bf16x4*)(smV + (dt * 16 + l15) * 68 + w * 16 + 4 * lg) = h;
    }
    __syncthreads();
    int tt = tid >> 7, c2 = (tid >> 3) & 15, j0 = (tid & 7) * 8;
    int dt = c2 >> 1, ks = c2 & 1;
    char* dst = KV + ((size_t)(b * 128 + t0 + tt)) * 32768 + 16384
                + c2 * 1024 + j0 * 16;
#pragma unroll
    for (int u = 0; u < 8; ++u) {
      int l = j0 + u;
      // slot e: sl = tt*32 + 16ks + 4*(l>>5) + (e&3) + 8*(e>>2)
      const bf16* p = smV + (dt * 32 + (l & 31)) * 68 + tt * 32
                      + ks * 16 + 4 * (l >> 5);
      bf16x4 lo = *(const bf16x4*)p;
      bf16x4 hi4 = *(const bf16x4*)(p + 8);
      bf16x8 v8 = __builtin_shufflevector(lo, hi4, 0, 1, 2, 3, 4, 5, 6, 7);
      *(bf16x8*)(dst + u * 16) = v8;
    }
  }
}

// ---------------------------------------------------------------------------
// Kernel 3: flash attention, 32x32x16 MFMA. 4 waves x 32 q (QBLK=128),
//   KVBLK=32. K double-buffered in LDS (2x16KB, gld_lds); V fragments
//   loaded DIRECTLY global->VGPR (8-frag time-shared window) — all 4 waves
//   read the same 16KB V tile (L1-served). One vmcnt(0)+barrier per tile.
// ---------------------------------------------------------------------------
__global__ __launch_bounds__(256, 2) void attn_kernel(
    const bf16* __restrict__ Qb, const char* __restrict__ KV,
    f16* __restrict__ P, float* __restrict__ ml, int nsplit, int ntiles) {
  __shared__ __align__(16) char smem[32768];  // K dbuf: 2 x 16KB

  int id = blockIdx.x;
  int b, sp, qb;
  if (nsplit == 4)      { int g = id & 15; b = g & 3;  sp = g >> 2; qb = id >> 4; }
  else if (nsplit == 2) { int g = id & 7;  b = g >> 1; sp = g & 1;  qb = id >> 3; }
  else                  { b = id & 3; sp = 0; qb = id >> 2; }

  int tid = threadIdx.x;
  int w = tid >> 6, lane = tid & 63, hi = lane >> 5, l31 = lane & 31;

  const char* kvsrc = KV + ((size_t)(b * 128 + sp * ntiles)) * 32768;

  // per-lane q row; Q as B-operand: slot (l,e) = Q[q=l31][k=16c+8hi+e]
  int qrow = b * S_LEN + qb * 128 + w * 32 + l31;
  const bf16* Qr = Qb + (size_t)qrow * HDIM;
  bf16x8 qf[16];
#pragma unroll
  for (int c = 0; c < 16; ++c)
    qf[c] = *(const bf16x8*)(Qr + c * 16 + hi * 8);

  f32x16 acc[8];
#pragma unroll
  for (int dt = 0; dt < 8; ++dt)
#pragma unroll
    for (int r = 0; r < 16; ++r) acc[dt][r] = 0.f;
  float lsum = 0.f;
  const float C = 0.09016844005556021f;  // (1/16) * log2(e)

  // prologue: stage K(0) -> buf 0 (16KB: 4 x 4KB rounds)
#pragma unroll
  for (int i = 0; i < 4; ++i)
    gld_lds16(kvsrc + i * 4096 + tid * 16, smem + i * 4096 + tid * 16);
  BAR_VMCNT0();

  for (int t = 0; t < ntiles; ++t) {
    int cur = (t & 1) << 14;
    const char* kb = smem + cur;
    const char* vsrc = kvsrc + (size_t)t * 32768 + 16384;
    bool pre = (t + 1 < ntiles);

    if (pre) {                      // issue K(t+1) -> other buf
      const char* s2 = kvsrc + (size_t)(t + 1) * 32768;
      char* d2 = smem + (cur ^ 16384);
#pragma unroll
      for (int i = 0; i < 4; ++i)
        gld_lds16(s2 + i * 4096 + tid * 16, d2 + i * 4096 + tid * 16);
    }

    // V fragments dt 0-3 -> register window (compiler-scheduled waits)
    bf16x8 vf[8];
#pragma unroll
    for (int j = 0; j < 8; ++j)
      vf[j] = *(const bf16x8*)(vsrc + j * 1024 + lane * 16);

    // S^T = K . Q^T : one 32x32 tile, K-dim 256 = 16 x (K=16)
    f32x16 st;
#pragma unroll
    for (int r = 0; r < 16; ++r) st[r] = 0.f;
    __builtin_amdgcn_s_setprio(1);
#pragma unroll
    for (int c = 0; c < 16; ++c) {
      bf16x8 kf = *(const bf16x8*)(kb + c * 1024 + lane * 16);
      st = mfma32(kf, qf[c], st);
    }
    __builtin_amdgcn_s_setprio(0);

    // softmax: lane owns q=l31, kv(reg) = (reg&3)+8*(reg>>2)+4*hi
    float p[16];
    float ps = 0.f;
#pragma unroll
    for (int r = 0; r < 16; ++r) {
      p[r] = fast_exp2(st[r] * C);
      ps += p[r];
    }
    lsum += ps;
    // P^T B-frags: pi-permuted V pack makes pf[ks][e] = p[e + 8ks]
    bf16x8 pf[2];
#pragma unroll
    for (int ks = 0; ks < 2; ++ks)
#pragma unroll
      for (int e = 0; e < 8; ++e) pf[ks][e] = (bf16)p[e + 8 * ks];

    // PV part A: d-blocks 0-3 from the register window
    __builtin_amdgcn_s_setprio(1);
#pragma unroll
    for (int dt = 0; dt < 4; ++dt) {
      acc[dt] = mfma32(vf[dt * 2 + 0], pf[0], acc[dt]);
      acc[dt] = mfma32(vf[dt * 2 + 1], pf[1], acc[dt]);
    }
    __builtin_amdgcn_s_setprio(0);

    // reload window with V fragments dt 4-7 (WAR safe: MFMAs read at issue)
#pragma unroll
    for (int j = 0; j < 8; ++j)
      vf[j] = *(const bf16x8*)(vsrc + (8 + j) * 1024 + lane * 16);

    // PV part B: d-blocks 4-7
    __builtin_amdgcn_s_setprio(1);
#pragma unroll
    for (int dt = 0; dt < 4; ++dt) {
      acc[4 + dt] = mfma32(vf[dt * 2 + 0], pf[0], acc[4 + dt]);
      acc[4 + dt] = mfma32(vf[dt * 2 + 1], pf[1], acc[4 + dt]);
    }
    __builtin_amdgcn_s_setprio(0);

    // K(t+1) landed + all waves done with K(t) -> swap buffers
    BAR_VMCNT0();
  }

  // epilogue: lane pair (l, l+32) holds complementary kv halves of q=l31
  lsum += __shfl_xor(lsum, 32, 64);
  f16* prow = P + (size_t)sp * PSTRIDE + (size_t)qrow * HDIM;
#pragma unroll
  for (int dt = 0; dt < 8; ++dt)
#pragma unroll
    for (int rb = 0; rb < 4; ++rb) {
      // d = dt*32 + (reg&3) + 8*rb + 4*hi, reg = rb*4 + j
      f16x4 h = {(f16)acc[dt][rb * 4 + 0], (f16)acc[dt][rb * 4 + 1],
                 (f16)acc[dt][rb * 4 + 2], (f16)acc[dt][rb * 4 + 3]};
      *(f16x4*)(prow + dt * 32 + rb * 8 + 4 * hi) = h;
    }
  if (lane < 32) ml[sp * 16384 + qrow] = lsum;
}

// ---------------------------------------------------------------------------
// Kernel 4: combine fp16 partials + normalize -> f32 d_out
// ---------------------------------------------------------------------------
__global__ __launch_bounds__(256) void combine_kernel(
    float* __restrict__ out, const f16* __restrict__ P,
    const float* __restrict__ ml, int nsplit) {
  int chunk = blockIdx.x * 256 + threadIdx.x;  // 524288 chunks of 8 elems
  int q = chunk >> 5;
  size_t base = (size_t)chunk * 8;

  float l = 0.f;
  float o[8] = {0.f, 0.f, 0.f, 0.f, 0.f, 0.f, 0.f, 0.f};
  for (int sp = 0; sp < nsplit; ++sp) {
    l += ml[sp * 16384 + q];
    f16x8 v = *(const f16x8*)(P + sp * PSTRIDE + base);
#pragma unroll
    for (int j = 0; j < 8; ++j) o[j] += (float)v[j];
  }
  float inv = 1.0f / l;
  f32x4 o0 = {o[0] * inv, o[1] * inv, o[2] * inv, o[3] * inv};
  f32x4 o1 = {o[4] * inv, o[5] * inv, o[6] * inv, o[7] * inv};
  *(f32x4*)(out + base) = o0;
  *(f32x4*)(out + base + 4) = o1;
}

// ---------------------------------------------------------------------------
extern "C" void kernel_launch(void* const* d_in, const int* in_sizes, int n_in,
                              void* d_out, int out_size, void* d_ws, size_t ws_size,
                              hipStream_t stream) {
  (void)in_sizes; (void)n_in; (void)out_size;
  const float* x  = (const float*)d_in[0];
  const float* Wq = (const float*)d_in[1];
  const float* bq = (const float*)d_in[2];
  const float* Wk = (const float*)d_in[3];
  const float* bk = (const float*)d_in[4];
  const float* Wv = (const float*)d_in[5];
  const float* bv = (const float*)d_in[6];

  char* ws = (char*)d_ws;
  bf16*  Qb = (bf16*)(ws);                               // 8 MB [16384][256]
  char*  KV = ws + (8u << 20);                           // 16 MB [4][128][32KB]
  bf16*  WT = (bf16*)(ws + (24u << 20));                 // 384 KB
  float* ml = (float*)(ws + (24u << 20) + (512u << 10)); // 256 KB
  f16*   P  = (f16*)(ws + (26u << 20));                  // nsplit x 8 MB fp16

  size_t need4 = ((size_t)26 << 20) + 4 * ((size_t)8 << 20);
  size_t need2 = ((size_t)26 << 20) + 2 * ((size_t)8 << 20);
  int nsplit = (ws_size >= need4) ? 4 : (ws_size >= need2) ? 2 : 1;
  int ntiles = (S_LEN / nsplit) / 32;
  int nblocks = 128 * nsplit;

  wt_kernel<<<192, 256, 0, stream>>>(Wq, Wk, Wv, WT);
  proj_kernel<<<dim3(256, 3), 256, 0, stream>>>(x, WT, bq, bk, bv, Qb, KV);
  attn_kernel<<<nblocks, 256, 0, stream>>>(Qb, KV, P, ml, nsplit, ntiles);
  combine_kernel<<<2048, 256, 0, stream>>>((float*)d_out, P, ml, nsplit);
}

// Round 11
// 108.878 us; speedup vs baseline: 1.1505x; 1.1505x over previous
//
#include <hip/hip_runtime.h>
#include <hip/hip_bf16.h>
#include <stdint.h>
#include <stddef.h>

// ---------------------------------------------------------------------------
// TimeSeriesAttention: out = softmax((x Wq + bq)(x Wk + bk)^T / 16) (x Wv + bv)
// B=4, S=4096, H=256, fp32 in/out.
// v11: back to v6 16x16 fragment math (best attn: 74.2us). New tile loop:
//      512-thr block (8 waves, QBLK=256), LDS 128KB = 2 pair-slots x 64KB,
//      TWO 32-kv tiles per barrier (pair-amortized overhead, halved staged
//      writes). Register footprint per wave unchanged -> 2 waves/SIMD kept.
// ---------------------------------------------------------------------------

typedef __bf16 bf16;
typedef _Float16 f16;
typedef __attribute__((ext_vector_type(4))) __bf16 bf16x4;
typedef __attribute__((ext_vector_type(8))) __bf16 bf16x8;
typedef __attribute__((ext_vector_type(4))) float f32x4;
typedef __attribute__((ext_vector_type(4))) _Float16 f16x4;
typedef __attribute__((ext_vector_type(8))) _Float16 f16x8;

#define S_LEN 4096
#define HDIM  256
#define PSTRIDE ((size_t)16384 * 256)   // elems per fp16 partial buffer (8MB)

__device__ __forceinline__ f32x4 mfma16(bf16x8 a, bf16x8 b, f32x4 c) {
  return __builtin_amdgcn_mfma_f32_16x16x32_bf16(a, b, c, 0, 0, 0);
}

__device__ __forceinline__ void gld_lds16(const void* g, void* l) {
  __builtin_amdgcn_global_load_lds(
      (const __attribute__((address_space(1))) void*)g,
      (__attribute__((address_space(3))) void*)l, 16, 0, 0);
}

__device__ __forceinline__ float fast_exp2(float x) {
  float r;
  asm("v_exp_f32 %0, %1" : "=v"(r) : "v"(x));
  return r;
}

// ---------------------------------------------------------------------------
// Kernel 1: WT_m[d][h] = (bf16) W_m[h][d].  192 blocks = 3 m x 64 (32x32) tiles.
// ---------------------------------------------------------------------------
__global__ __launch_bounds__(256) void wt_kernel(
    const float* __restrict__ Wq, const float* __restrict__ Wk,
    const float* __restrict__ Wv, bf16* __restrict__ WT) {
  __shared__ float tile[32][33];
  int bid = blockIdx.x;
  int m = bid >> 6;
  int t = bid & 63;
  int hb = (t >> 3) * 32;
  int db = (t & 7) * 32;
  const float* W = (m == 0) ? Wq : (m == 1) ? Wk : Wv;
  bf16* o = WT + m * 65536;
  int ty = threadIdx.x >> 3;
  int tx = threadIdx.x & 7;
  float4 v = *(const float4*)(W + (size_t)(hb + ty) * 256 + db + tx * 4);
  tile[ty][tx * 4 + 0] = v.x; tile[ty][tx * 4 + 1] = v.y;
  tile[ty][tx * 4 + 2] = v.z; tile[ty][tx * 4 + 3] = v.w;
  __syncthreads();
  bf16x4 h = {(bf16)tile[tx * 4 + 0][ty], (bf16)tile[tx * 4 + 1][ty],
              (bf16)tile[tx * 4 + 2][ty], (bf16)tile[tx * 4 + 3][ty]};
  *(bf16x4*)(o + (size_t)(db + ty) * 256 + hb + tx * 4) = h;
}

// ---------------------------------------------------------------------------
// Kernel 2: fused QKV projection (v6 structure, 16x16 fragment emit).
//   m=1: K frag c=ks*2+kvf slot (l,e):
//        = K[t*32+(c&1)*16+(l&15)][(c>>1)*32+(l>>4)*8+e]
//   m=2: V frag dt slot (l,e):
//        = V[t*32+16*(e>>2)+4*(l>>4)+(e&3)][dt*16+(l&15)]
// ---------------------------------------------------------------------------
__global__ __launch_bounds__(256, 3) void proj_kernel(
    const float* __restrict__ x, const bf16* __restrict__ WT,
    const float* __restrict__ bq, const float* __restrict__ bk,
    const float* __restrict__ bv,
    bf16* __restrict__ Qb, char* __restrict__ KV) {
  __shared__ __align__(16) char smem[34816];
  int tid = threadIdx.x;
  int row0 = blockIdx.x * 64;
  int m = blockIdx.y;

#pragma unroll
  for (int i = 0; i < 16; ++i) {
    int c = i * 256 + tid;
    int r = c >> 6, c4 = c & 63;
    float4 v = *(const float4*)(x + (size_t)(row0 + r) * 256 + c4 * 4);
    bf16x4 b4 = {(bf16)v.x, (bf16)v.y, (bf16)v.z, (bf16)v.w};
    *(bf16x4*)(smem + r * 512 + ((c4 * 8) ^ ((r & 7) << 4))) = b4;
  }
  __syncthreads();

  int w = tid >> 6, lane = tid & 63, lg = lane >> 4, l15 = lane & 15;
  int ar = w * 16 + l15;
  int swz = (l15 & 7) << 4;
  bf16x8 af[8];
#pragma unroll
  for (int ks = 0; ks < 8; ++ks)
    af[ks] = *(const bf16x8*)(smem + ar * 512 + ((ks * 64 + lg * 16) ^ swz));
  __syncthreads();

  int b = row0 >> 12, t0 = (row0 & 4095) >> 5;
  const bf16* Wm = WT + m * 65536;
  const float* bias = (m == 0) ? bq : (m == 1) ? bk : bv;

#pragma unroll
  for (int i = 0; i < 4; ++i) {
    int c = w * 4 + i;
    gld_lds16(Wm + (c * 16 + l15) * 256 + lg * 8, smem + c * 1024 + lane * 16);
  }
  __syncthreads();

  f32x4 acc[16];
#pragma unroll
  for (int dt = 0; dt < 16; ++dt) acc[dt] = f32x4{0.f, 0.f, 0.f, 0.f};

  for (int ks = 0; ks < 8; ++ks) {
    const char* wb = smem + (ks & 1) * 16384;
    if (ks + 1 < 8) {
      char* wn = smem + ((ks + 1) & 1) * 16384;
#pragma unroll
      for (int i = 0; i < 4; ++i) {
        int c = w * 4 + i;
        gld_lds16(Wm + (c * 16 + l15) * 256 + (ks + 1) * 32 + lg * 8,
                  wn + c * 1024 + lane * 16);
      }
    }
    __builtin_amdgcn_s_setprio(1);
#pragma unroll
    for (int dt = 0; dt < 16; ++dt) {
      bf16x8 wf = *(const bf16x8*)(wb + dt * 1024 + lane * 16);
      acc[dt] = mfma16(af[ks], wf, acc[dt]);
    }
    __builtin_amdgcn_s_setprio(0);
    __syncthreads();
  }

  if (m == 0) {
#pragma unroll
    for (int dt = 0; dt < 16; ++dt) {
      float bb = bias[dt * 16 + l15];
#pragma unroll
      for (int rr = 0; rr < 4; ++rr) {
        int srow = row0 + w * 16 + 4 * lg + rr;
        Qb[(size_t)srow * 256 + dt * 16 + l15] = (bf16)(acc[dt][rr] + bb);
      }
    }
  } else if (m == 1) {
    // K: tile [s_local][d] in LDS (stride 264), emit 16x16 fragment order
    bf16* sm16 = (bf16*)smem;
#pragma unroll
    for (int dt = 0; dt < 16; ++dt) {
      float bb = bias[dt * 16 + l15];
#pragma unroll
      for (int rr = 0; rr < 4; ++rr) {
        int sl = w * 16 + 4 * lg + rr;
        sm16[sl * 264 + dt * 16 + l15] = (bf16)(acc[dt][rr] + bb);
      }
    }
    __syncthreads();
    int tt = tid >> 7, c = (tid >> 3) & 15, j0 = (tid & 7) * 8;
    char* dst = KV + ((size_t)(b * 128 + t0 + tt)) * 32768 + c * 1024 + j0 * 16;
#pragma unroll
    for (int u = 0; u < 8; ++u) {
      int l = j0 + u;
      bf16x8 v8 = *(const bf16x8*)(sm16 + (tt * 32 + (c & 1) * 16 + (l & 15)) * 264
                                   + (c >> 1) * 32 + (l >> 4) * 8);
      *(bf16x8*)(dst + u * 16) = v8;
    }
  } else {
    // V: transposed tile smV[d][sl] (stride 68), emit as bf16x4 pairs
    bf16* smV = (bf16*)smem;
#pragma unroll
    for (int dt = 0; dt < 16; ++dt) {
      float bb = bias[dt * 16 + l15];
      bf16x4 h = {(bf16)(acc[dt][0] + bb), (bf16)(acc[dt][1] + bb),
                  (bf16)(acc[dt][2] + bb), (bf16)(acc[dt][3] + bb)};
      *(bf16x4*)(smV + (dt * 16 + l15) * 68 + w * 16 + 4 * lg) = h;
    }
    __syncthreads();
    int tt = tid >> 7, c = (tid >> 3) & 15, j0 = (tid & 7) * 8;
    char* dst = KV + ((size_t)(b * 128 + t0 + tt)) * 32768 + 16384
                + c * 1024 + j0 * 16;
#pragma unroll
    for (int u = 0; u < 8; ++u) {
      int l = j0 + u;
      const bf16* p = smV + (c * 16 + (l & 15)) * 68 + tt * 32 + 4 * (l >> 4);
      bf16x4 lo = *(const bf16x4*)p;
      bf16x4 hi = *(const bf16x4*)(p + 16);
      bf16x8 v8 = __builtin_shufflevector(lo, hi, 0, 1, 2, 3, 4, 5, 6, 7);
      *(bf16x8*)(dst + u * 16) = v8;
    }
  }
}

// ---------------------------------------------------------------------------
// Kernel 3: flash attention. 512 thr = 8 waves x 32 q (QBLK=256), KVBLK=32,
//   LDS 128KB = 2 pair-slots x 64KB: TWO tiles computed per barrier.
//   Stage pair ip+1 at loop top (2 tile-times to land), one __syncthreads
//   per pair. Per-wave math identical to v6 (16x16, verified).
// ---------------------------------------------------------------------------
__global__ __launch_bounds__(512, 2) void attn_kernel(
    const bf16* __restrict__ Qb, const char* __restrict__ KV,
    f16* __restrict__ P, float* __restrict__ ml, int nsplit, int ntiles) {
  __shared__ __align__(16) char smem[131072];  // 2 pair-slots x 64KB

  int id = blockIdx.x;
  int b, sp, qb;
  if (nsplit == 4)      { int g = id & 15; b = g & 3;  sp = g >> 2; qb = id >> 4; }
  else if (nsplit == 2) { int g = id & 7;  b = g >> 1; sp = g & 1;  qb = id >> 3; }
  else                  { b = id & 3; sp = 0; qb = id >> 2; }

  int tid = threadIdx.x;
  int w = tid >> 6, lane = tid & 63, lg = lane >> 4, l15 = lane & 15;

  const char* kvsrc = KV + ((size_t)(b * 128 + sp * ntiles)) * 32768;

  // Q fragments: q = qb*256 + w*32 + qs*16 + l15
  int qrow0 = b * S_LEN + qb * 256 + w * 32 + l15;
  bf16x8 qf[2][8];
#pragma unroll
  for (int qs = 0; qs < 2; ++qs) {
    const bf16* Qr = Qb + (size_t)(qrow0 + qs * 16) * HDIM;
#pragma unroll
    for (int ks = 0; ks < 8; ++ks)
      qf[qs][ks] = *(const bf16x8*)(Qr + ks * 32 + lg * 8);
  }

  f32x4 acc[2][16];
#pragma unroll
  for (int qs = 0; qs < 2; ++qs)
#pragma unroll
    for (int dt = 0; dt < 16; ++dt) acc[qs][dt] = f32x4{0.f, 0.f, 0.f, 0.f};
  float lsum[2] = {0.f, 0.f};
  const float C = 0.09016844005556021f;  // (1/16) * log2(e)

  // prologue: stage pair 0 (64KB) -> pair-slot 0; 8 x 8KB rounds
#pragma unroll
  for (int i = 0; i < 8; ++i)
    gld_lds16(kvsrc + i * 8192 + tid * 16, smem + i * 8192 + tid * 16);
  __syncthreads();

  int npairs = ntiles >> 1;
  for (int ip = 0; ip < npairs; ++ip) {
    const char* pb = smem + (ip & 1) * 65536;
    if (ip + 1 < npairs) {          // stage next pair into the other slot
      const char* s2 = kvsrc + (size_t)(ip + 1) * 65536;
      char* d2 = smem + ((ip + 1) & 1) * 65536;
#pragma unroll
      for (int i = 0; i < 8; ++i)
        gld_lds16(s2 + i * 8192 + tid * 16, d2 + i * 8192 + tid * 16);
    }

#pragma unroll
    for (int half = 0; half < 2; ++half) {
      const char* kb = pb + half * 32768;
      const char* vb = kb + 16384;

      // S^T = K . Q^T (frag-linear reads, 0 conflicts)
      f32x4 st[2][2];
      st[0][0] = f32x4{0.f, 0.f, 0.f, 0.f}; st[0][1] = st[0][0];
      st[1][0] = st[0][0];                   st[1][1] = st[0][0];
      __builtin_amdgcn_s_setprio(1);
#pragma unroll
      for (int ks = 0; ks < 8; ++ks) {
        bf16x8 k0 = *(const bf16x8*)(kb + (ks * 2 + 0) * 1024 + lane * 16);
        bf16x8 k1 = *(const bf16x8*)(kb + (ks * 2 + 1) * 1024 + lane * 16);
        st[0][0] = mfma16(k0, qf[0][ks], st[0][0]);
        st[1][0] = mfma16(k0, qf[1][ks], st[1][0]);
        st[0][1] = mfma16(k1, qf[0][ks], st[0][1]);
        st[1][1] = mfma16(k1, qf[1][ks], st[1][1]);
      }
      __builtin_amdgcn_s_setprio(0);

      // no-max softmax: p = exp2(s*C); per-lane deferred l
      bf16x8 pf[2];
#pragma unroll
      for (int qs = 0; qs < 2; ++qs) {
        float ps = 0.f;
#pragma unroll
        for (int e = 0; e < 8; ++e) {
          float pv = fast_exp2(st[qs][e >> 2][e & 3] * C);
          ps += pv;
          pf[qs][e] = (bf16)pv;   // kv = 16*(e>>2) + 4*lg + (e&3)
        }
        lsum[qs] += ps;
      }

      // O^T += V^T . P^T
      __builtin_amdgcn_s_setprio(1);
#pragma unroll
      for (int dt = 0; dt < 16; ++dt) {
        bf16x8 vf = *(const bf16x8*)(vb + dt * 1024 + lane * 16);
        acc[0][dt] = mfma16(vf, pf[0], acc[0][dt]);
        acc[1][dt] = mfma16(vf, pf[1], acc[1][dt]);
      }
      __builtin_amdgcn_s_setprio(0);
    }
    __syncthreads();                // pair consumed + next pair landed
  }

  f16* Pp = P + (size_t)sp * PSTRIDE;
#pragma unroll
  for (int qs = 0; qs < 2; ++qs) {
    float l = lsum[qs];
    l += __shfl_xor(l, 16, 64);
    l += __shfl_xor(l, 32, 64);
    int qrow = qrow0 + qs * 16;
    f16* prow = Pp + (size_t)qrow * HDIM;
#pragma unroll
    for (int dt = 0; dt < 16; ++dt) {
      f32x4 a = acc[qs][dt];
      f16x4 h = {(f16)a[0], (f16)a[1], (f16)a[2], (f16)a[3]};
      *(f16x4*)(prow + dt * 16 + 4 * lg) = h;
    }
    if (lane < 16) ml[sp * 16384 + qrow] = l;
  }
}

// ---------------------------------------------------------------------------
// Kernel 4: combine fp16 partials + normalize -> f32 d_out
// ---------------------------------------------------------------------------
__global__ __launch_bounds__(256) void combine_kernel(
    float* __restrict__ out, const f16* __restrict__ P,
    const float* __restrict__ ml, int nsplit) {
  int chunk = blockIdx.x * 256 + threadIdx.x;  // 524288 chunks of 8 elems
  int q = chunk >> 5;
  size_t base = (size_t)chunk * 8;

  float l = 0.f;
  float o[8] = {0.f, 0.f, 0.f, 0.f, 0.f, 0.f, 0.f, 0.f};
  for (int sp = 0; sp < nsplit; ++sp) {
    l += ml[sp * 16384 + q];
    f16x8 v = *(const f16x8*)(P + sp * PSTRIDE + base);
#pragma unroll
    for (int j = 0; j < 8; ++j) o[j] += (float)v[j];
  }
  float inv = 1.0f / l;
  f32x4 o0 = {o[0] * inv, o[1] * inv, o[2] * inv, o[3] * inv};
  f32x4 o1 = {o[4] * inv, o[5] * inv, o[6] * inv, o[7] * inv};
  *(f32x4*)(out + base) = o0;
  *(f32x4*)(out + base + 4) = o1;
}

// ---------------------------------------------------------------------------
extern "C" void kernel_launch(void* const* d_in, const int* in_sizes, int n_in,
                              void* d_out, int out_size, void* d_ws, size_t ws_size,
                              hipStream_t stream) {
  (void)in_sizes; (void)n_in; (void)out_size;
  const float* x  = (const float*)d_in[0];
  const float* Wq = (const float*)d_in[1];
  const float* bq = (const float*)d_in[2];
  const float* Wk = (const float*)d_in[3];
  const float* bk = (const float*)d_in[4];
  const float* Wv = (const float*)d_in[5];
  const float* bv = (const float*)d_in[6];

  char* ws = (char*)d_ws;
  bf16*  Qb = (bf16*)(ws);                               // 8 MB [16384][256]
  char*  KV = ws + (8u << 20);                           // 16 MB [4][128][32KB]
  bf16*  WT = (bf16*)(ws + (24u << 20));                 // 384 KB
  float* ml = (float*)(ws + (24u << 20) + (512u << 10)); // 256 KB
  f16*   P  = (f16*)(ws + (26u << 20));                  // nsplit x 8 MB fp16

  size_t need4 = ((size_t)26 << 20) + 4 * ((size_t)8 << 20);
  size_t need2 = ((size_t)26 << 20) + 2 * ((size_t)8 << 20);
  int nsplit = (ws_size >= need4) ? 4 : (ws_size >= need2) ? 2 : 1;
  int ntiles = (S_LEN / nsplit) / 32;
  int nblocks = 64 * nsplit;   // (16384/256 q-blocks) x nsplit

  wt_kernel<<<192, 256, 0, stream>>>(Wq, Wk, Wv, WT);
  proj_kernel<<<dim3(256, 3), 256, 0, stream>>>(x, WT, bq, bk, bv, Qb, KV);
  attn_kernel<<<nblocks, 512, 0, stream>>>(Qb, KV, P, ml, nsplit, ntiles);
  combine_kernel<<<2048, 256, 0, stream>>>((float*)d_out, P, ml, nsplit);
}